// Round 12
// baseline (149.307 us; speedup 1.0000x reference)
//
#include <hip/hip_runtime.h>

// SGC: out = A_norm^2 (x W) + bias   (linearity: A^2 x W = A^2 (xW)).
// N=100000 nodes, E=1000000 edges, D=64 features, fp32 in/out.
// CSR build = two-level LDS-binned counting sort, ZERO per-edge global
// atomics. Round-12: (1) hop edge loop = predicated 8-wide batches (old
// serial remainder cost ~700cy/edge on in-order issue); (2) kD_deg pass
// computes dinv before kB_sort so the sort writes final normalized
// weights (k_norm pass deleted); (3) hop2 nontemporal stores.

constexpr int kN = 100000;
constexpr int kD = 64;
constexpr int BSHIFT = 9;                    // 512 nodes per coarse bucket
constexpr int NBUCK = (kN + 511) >> BSHIFT;  // 196
constexpr int CHUNK = 4096;                  // pass-A edges per block
constexpr int XW_ROWS = 128;                 // k_xw rows per block

__device__ __forceinline__ float bf2f(unsigned short u) {
    return __uint_as_float(((unsigned)u) << 16);
}
__device__ __forceinline__ unsigned short f2bf(float f) {  // RNE
    unsigned b = __float_as_uint(f);
    b += 0x7FFF + ((b >> 16) & 1);
    return (unsigned short)(b >> 16);
}

// ---- pass A1: per-block bucket histogram (no global atomics) ----
__global__ __launch_bounds__(256) void kA_count(const int* __restrict__ row,
                                                int* __restrict__ bc, int nblk, int E) {
    __shared__ int hist[256];
    int t = threadIdx.x;
    hist[t] = 0;
    __syncthreads();
    int g0 = blockIdx.x * CHUNK;
    int n = min(CHUNK, E - g0);
    for (int i = t; i < n; i += 256) {
        atomicAdd(&hist[row[g0 + i] >> BSHIFT], 1);
    }
    __syncthreads();
    if (t < NBUCK) bc[t * nblk + blockIdx.x] = hist[t];
}

// ---- pass A2a: per-bucket parallel exclusive scan over blocks ----
__global__ __launch_bounds__(256) void kA_scanB(int* __restrict__ bc,
                                                int* __restrict__ tot, int nblk) {
    __shared__ int sh[256];
    int b = blockIdx.x;
    int t = threadIdx.x;
    int* p = bc + (size_t)b * nblk;
    int ipt = (nblk + 255) >> 8;  // items per thread (1 for nblk<=256)
    int s0 = t * ipt;
    int s1 = min(s0 + ipt, nblk);
    int lsum = 0;
    for (int k = s0; k < s1; ++k) lsum += p[k];
    sh[t] = lsum;
    __syncthreads();
    for (int off = 1; off < 256; off <<= 1) {
        int add = (t >= off) ? sh[t - off] : 0;
        __syncthreads();
        sh[t] += add;
        __syncthreads();
    }
    int run = sh[t] - lsum;  // exclusive prefix of this thread's segment
    for (int k = s0; k < s1; ++k) {
        int v = p[k];
        p[k] = run;
        run += v;
    }
    if (t == 255) tot[b] = sh[255];
}

// ---- pass A2b: exclusive scan of bucket totals -> base[] ----
__global__ __launch_bounds__(256) void kA_scanT(const int* __restrict__ tot,
                                                int* __restrict__ base) {
    __shared__ int sh[256];
    int t = threadIdx.x;
    int v = (t < NBUCK) ? tot[t] : 0;
    sh[t] = v;
    __syncthreads();
    for (int off = 1; off < 256; off <<= 1) {
        int add = (t >= off) ? sh[t - off] : 0;
        __syncthreads();
        sh[t] += add;
        __syncthreads();
    }
    if (t < NBUCK) base[t] = sh[t] - v;
}

// ---- pass A3: bucket-major placement via LDS staging, coalesced run flush
// tmp[pos] = { col | (row&511)<<17 , w_bits }
__global__ __launch_bounds__(256) void kA_place(const int* __restrict__ row,
                                                const int* __restrict__ col,
                                                const float* __restrict__ w,
                                                const int* __restrict__ bc,
                                                const int* __restrict__ base, int nblk,
                                                int2* __restrict__ tmp, int E) {
    __shared__ int hist[256];
    __shared__ int lbase[256];
    __shared__ int gb[256];
    __shared__ int cur[256];
    __shared__ int2 stage[CHUNK];
    __shared__ unsigned char bkt[CHUNK];
    int t = threadIdx.x;
    hist[t] = 0;
    __syncthreads();
    int g0 = blockIdx.x * CHUNK;
    int n = min(CHUNK, E - g0);
    for (int i = t; i < n; i += 256) {
        atomicAdd(&hist[row[g0 + i] >> BSHIFT], 1);
    }
    __syncthreads();
    // exclusive scan hist -> lbase (local bucket starts within this chunk)
    int v = hist[t];
    lbase[t] = v;
    __syncthreads();
    for (int off = 1; off < 256; off <<= 1) {
        int add = (t >= off) ? lbase[t - off] : 0;
        __syncthreads();
        lbase[t] += add;
        __syncthreads();
    }
    int excl = lbase[t] - v;
    __syncthreads();
    lbase[t] = excl;
    cur[t] = excl;
    if (t < NBUCK) gb[t] = base[t] + bc[t * nblk + blockIdx.x];  // block's run start
    __syncthreads();
    // place edges bucket-major in LDS (LDS atomics only)
    for (int i = t; i < n; i += 256) {
        int r = row[g0 + i];
        int c = col[g0 + i];
        float wv = w[g0 + i];
        int b = r >> BSHIFT;
        int lp = atomicAdd(&cur[b], 1);
        stage[lp] = make_int2(c | ((r & 511) << 17), __float_as_int(wv));
        bkt[lp] = (unsigned char)b;
    }
    __syncthreads();
    // flush: consecutive i within a bucket run -> consecutive global addresses
    for (int i = t; i < n; i += 256) {
        int b = bkt[i];
        tmp[gb[b] + (i - lbase[b])] = stage[i];
    }
}

// ---- pass A4: per-bucket deg/dinv from tmp (LDS float atomics) ----
__global__ __launch_bounds__(512) void kD_deg(const int2* __restrict__ tmp,
                                              const int* __restrict__ base,
                                              float* __restrict__ dinv, int E) {
    __shared__ float degs[512];
    int b = blockIdx.x;
    int t = threadIdx.x;
    degs[t] = 0.0f;
    __syncthreads();
    int gbase = base[b];
    int gend = (b == NBUCK - 1) ? E : base[b + 1];
    int node0 = b << BSHIFT;
    int nloc = min(512, kN - node0);
    for (int i = gbase + t; i < gend; i += 512) {
        int2 e = tmp[i];
        atomicAdd(&degs[(e.x >> 17) & 511], __int_as_float(e.y));
    }
    __syncthreads();
    if (t < nloc) {
        float d = 1.0f + degs[t];
        dinv[node0 + t] = (d > 0.0f) ? rsqrtf(d) : 0.0f;
    }
}

// ---- pass B: per-bucket fine counting sort + start[] ----
// writes FINAL ecw = {byte offset col<<7, dinv[row]*w*dinv[col]} (dinv ready).
__global__ __launch_bounds__(512) void kB_sort(const int2* __restrict__ tmp,
                                               const int* __restrict__ base,
                                               const float* __restrict__ dinv,
                                               int2* __restrict__ ecw,
                                               int* __restrict__ start, int E) {
    __shared__ int hist[512];
    __shared__ int cur[512];
    int b = blockIdx.x;
    int t = threadIdx.x;
    int gbase = base[b];
    int gend = (b == NBUCK - 1) ? E : base[b + 1];
    int size = gend - gbase;
    int node0 = b << BSHIFT;
    int nloc = min(512, kN - node0);
    hist[t] = 0;
    __syncthreads();
    for (int i = t; i < size; i += 512) {
        atomicAdd(&hist[(tmp[gbase + i].x >> 17) & 511], 1);
    }
    __syncthreads();
    // exclusive scan hist -> cur
    int v = hist[t];
    hist[t] = v;
    __syncthreads();
    for (int off = 1; off < 512; off <<= 1) {
        int add = (t >= off) ? hist[t - off] : 0;
        __syncthreads();
        hist[t] += add;
        __syncthreads();
    }
    int excl = hist[t] - v;
    __syncthreads();
    cur[t] = excl;
    __syncthreads();
    if (t < nloc) start[node0 + t] = gbase + excl;
    if (b == 0 && t == 0) start[kN] = E;
    // scatter within bucket, applying full normalization
    for (int i = t; i < size; i += 512) {
        int2 e = tmp[gbase + i];
        int c = e.x & 0x1FFFF;
        int rl = (e.x >> 17) & 511;
        float wn = dinv[node0 + rl] * __int_as_float(e.y) * dinv[c];
        int lp = atomicAdd(&cur[rl], 1);
        ecw[gbase + lp] = make_int2(c << 7, __float_as_int(wn));
    }
}

// ---- y = x @ W (fp32 in, bf16 out) ----
// lane = output column (W column in 64 VGPRs); 128 x-rows staged in LDS;
// per row: 16 broadcast b128 LDS reads + 64 FMAs; 2 rows in flight.
__global__ __launch_bounds__(256) void k_xw(const float* __restrict__ x,
                                            const float* __restrict__ W,
                                            unsigned short* __restrict__ y, int n) {
    __shared__ float Xs[XW_ROWS][kD];
    int t = threadIdx.x;
    int lane = t & 63;
    int wv = t >> 6;  // wave id 0..3
    int row0 = blockIdx.x * XW_ROWS;
    float Wc[kD];
#pragma unroll
    for (int k = 0; k < kD; ++k) Wc[k] = W[k * kD + lane];
    for (int i = t; i < XW_ROWS * (kD / 4); i += 256) {
        int r = i >> 4;
        int q = i & 15;
        float4 v = make_float4(0.0f, 0.0f, 0.0f, 0.0f);
        if (row0 + r < n)
            v = *reinterpret_cast<const float4*>(x + (size_t)(row0 + r) * kD + q * 4);
        *reinterpret_cast<float4*>(&Xs[r][q * 4]) = v;
    }
    __syncthreads();
    int rbase = wv * 32;  // this wave's 32 rows
#pragma unroll
    for (int rr = 0; rr < 32; rr += 2) {
        int r0 = rbase + rr;
        float acc0 = 0.0f, acc1 = 0.0f;
#pragma unroll
        for (int q = 0; q < 16; ++q) {  // broadcast reads: all lanes same addr
            float4 a = *reinterpret_cast<const float4*>(&Xs[r0][q * 4]);
            float4 b = *reinterpret_cast<const float4*>(&Xs[r0 + 1][q * 4]);
            acc0 = fmaf(a.x, Wc[q * 4 + 0], acc0);
            acc1 = fmaf(b.x, Wc[q * 4 + 0], acc1);
            acc0 = fmaf(a.y, Wc[q * 4 + 1], acc0);
            acc1 = fmaf(b.y, Wc[q * 4 + 1], acc1);
            acc0 = fmaf(a.z, Wc[q * 4 + 2], acc0);
            acc1 = fmaf(b.z, Wc[q * 4 + 2], acc1);
            acc0 = fmaf(a.w, Wc[q * 4 + 3], acc0);
            acc1 = fmaf(b.w, Wc[q * 4 + 3], acc1);
        }
        int gr = row0 + r0;
        if (gr < n) y[(size_t)gr * kD + lane] = f2bf(acc0);
        if (gr + 1 < n) y[(size_t)(gr + 1) * kD + lane] = f2bf(acc1);
    }
}

// ---- gather hop: 1 wave/node (scalarized), lane = feature ----
// Edge loop = predicated 8-wide batches: idx clamped to e-1 (same cache
// line as last real edge), weight zeroed for padding -> every load in the
// wave issues in parallel, no serial remainder chain.
template <typename OutWriter>
__device__ __forceinline__ void hop_body(const int* __restrict__ start,
                                         const int2* __restrict__ ecw,
                                         const float* __restrict__ dinv,
                                         const unsigned short* __restrict__ h_in,
                                         int n, OutWriter writeout) {
    int node = blockIdx.x * 4 + __builtin_amdgcn_readfirstlane(threadIdx.x >> 6);
    int lane = threadIdx.x & 63;
    if (node >= n) return;  // wave-uniform (1 wave = 1 node)
    const char* hb = (const char*)h_in;
    int lo = lane << 1;  // lane byte offset, loop-invariant
    float di = dinv[node];
    float self = bf2f(h_in[(size_t)node * kD + lane]);
    float acc = di * di * self;
    int s = start[node], e = start[node + 1];
    int em1 = e - 1;
    for (int j = s; j < e; j += 8) {
        int2 v0 = ecw[j];  // j < e always
        int2 v1 = ecw[min(j + 1, em1)];
        int2 v2 = ecw[min(j + 2, em1)];
        int2 v3 = ecw[min(j + 3, em1)];
        int2 v4 = ecw[min(j + 4, em1)];
        int2 v5 = ecw[min(j + 5, em1)];
        int2 v6 = ecw[min(j + 6, em1)];
        int2 v7 = ecw[min(j + 7, em1)];
        float g0 = bf2f(*(const unsigned short*)(hb + (unsigned)(v0.x + lo)));
        float g1 = bf2f(*(const unsigned short*)(hb + (unsigned)(v1.x + lo)));
        float g2 = bf2f(*(const unsigned short*)(hb + (unsigned)(v2.x + lo)));
        float g3 = bf2f(*(const unsigned short*)(hb + (unsigned)(v3.x + lo)));
        float g4 = bf2f(*(const unsigned short*)(hb + (unsigned)(v4.x + lo)));
        float g5 = bf2f(*(const unsigned short*)(hb + (unsigned)(v5.x + lo)));
        float g6 = bf2f(*(const unsigned short*)(hb + (unsigned)(v6.x + lo)));
        float g7 = bf2f(*(const unsigned short*)(hb + (unsigned)(v7.x + lo)));
        float w0 = __int_as_float(v0.y);
        float w1 = (j + 1 < e) ? __int_as_float(v1.y) : 0.0f;
        float w2 = (j + 2 < e) ? __int_as_float(v2.y) : 0.0f;
        float w3 = (j + 3 < e) ? __int_as_float(v3.y) : 0.0f;
        float w4 = (j + 4 < e) ? __int_as_float(v4.y) : 0.0f;
        float w5 = (j + 5 < e) ? __int_as_float(v5.y) : 0.0f;
        float w6 = (j + 6 < e) ? __int_as_float(v6.y) : 0.0f;
        float w7 = (j + 7 < e) ? __int_as_float(v7.y) : 0.0f;
        acc = fmaf(w0, g0, acc);
        acc = fmaf(w1, g1, acc);
        acc = fmaf(w2, g2, acc);
        acc = fmaf(w3, g3, acc);
        acc = fmaf(w4, g4, acc);
        acc = fmaf(w5, g5, acc);
        acc = fmaf(w6, g6, acc);
        acc = fmaf(w7, g7, acc);
    }
    writeout(node, lane, di, acc);
}

__global__ __launch_bounds__(256) void k_hop1(const int* __restrict__ start,
                                              const int2* __restrict__ ecw,
                                              const float* __restrict__ dinv,
                                              const unsigned short* __restrict__ h_in,
                                              unsigned short* __restrict__ h_out, int n) {
    hop_body(start, ecw, dinv, h_in, n,
             [=](int node, int lane, float di, float acc) {
                 h_out[(size_t)node * kD + lane] = f2bf(acc);
             });
}

__global__ __launch_bounds__(256) void k_hop2(const int* __restrict__ start,
                                              const int2* __restrict__ ecw,
                                              const float* __restrict__ dinv,
                                              const unsigned short* __restrict__ h_in,
                                              const float* __restrict__ bias,
                                              float* __restrict__ out, int n) {
    hop_body(start, ecw, dinv, h_in, n,
             [=](int node, int lane, float di, float acc) {
                 // out never re-read -> nontemporal, keep L2 for h1 gathers
                 __builtin_nontemporal_store(acc + bias[lane],
                                             &out[(size_t)node * kD + lane]);
             });
}

extern "C" void kernel_launch(void* const* d_in, const int* in_sizes, int n_in,
                              void* d_out, int out_size, void* d_ws, size_t ws_size,
                              hipStream_t stream) {
    const float* x    = (const float*)d_in[0];   // (N, 64)
    const int*   ei   = (const int*)d_in[1];     // (2, E)
    const float* ew   = (const float*)d_in[2];   // (E,)
    const float* W    = (const float*)d_in[3];   // (64, 64)
    const float* bias = (const float*)d_in[4];   // (64,)
    const int E = in_sizes[1] / 2;
    const int* row = ei;       // destination
    const int* col = ei + E;   // source

    const int nblk = (E + CHUNK - 1) / CHUNK;  // pass-A blocks (245 @ E=1M)

    // ws layout (1KB-aligned): base[256] | tot[256] | bc[NBUCK*nblk] |
    // start[kN+1] | dinv[kN] | ecw[E] int2 | y bf16 | h1 bf16 (tmp aliases h1)
    char* ws = (char*)d_ws;
    auto alloc = [&](size_t bytes) {
        char* p = ws;
        ws += ((bytes + 1023) & ~(size_t)1023);
        return p;
    };
    int*            base  = (int*)alloc(sizeof(int) * 256);
    int*            tot   = (int*)alloc(sizeof(int) * 256);
    int*            bc    = (int*)alloc(sizeof(int) * (size_t)NBUCK * nblk);
    int*            start = (int*)alloc(sizeof(int) * (kN + 1));
    float*          dinv  = (float*)alloc(sizeof(float) * kN);
    int2*           ecw   = (int2*)alloc(sizeof(int2) * (size_t)E);
    unsigned short* y     = (unsigned short*)alloc(sizeof(short) * (size_t)kN * kD);
    unsigned short* h1    = (unsigned short*)alloc(sizeof(short) * (size_t)kN * kD);
    int2*           tmp   = (int2*)h1;  // bucket-major staging, dead before hop1

    // dense linear first: y = x @ W (bf16)
    k_xw<<<(kN + XW_ROWS - 1) / XW_ROWS, 256, 0, stream>>>(x, W, y, kN);

    // CSR build (no per-edge global atomics)
    kA_count<<<nblk, 256, 0, stream>>>(row, bc, nblk, E);
    kA_scanB<<<NBUCK, 256, 0, stream>>>(bc, tot, nblk);
    kA_scanT<<<1, 256, 0, stream>>>(tot, base);
    kA_place<<<nblk, 256, 0, stream>>>(row, col, ew, bc, base, nblk, tmp, E);
    kD_deg<<<NBUCK, 512, 0, stream>>>(tmp, base, dinv, E);
    kB_sort<<<NBUCK, 512, 0, stream>>>(tmp, base, dinv, ecw, start, E);

    // 2 gather hops (weights fully pre-normalized, byte-offset cols)
    k_hop1<<<(kN + 3) / 4, 256, 0, stream>>>(start, ecw, dinv, y, h1, kN);
    k_hop2<<<(kN + 3) / 4, 256, 0, stream>>>(start, ecw, dinv, h1, bias,
                                             (float*)d_out, kN);
}

// Round 13
// 141.650 us; speedup vs baseline: 1.0541x; 1.0541x over previous
//
#include <hip/hip_runtime.h>

// SGC: out = A_norm^2 (x W) + bias   (linearity: A^2 x W = A^2 (xW)).
// N=100000 nodes, E=1000000 edges, D=64 features, fp32 in/out.
// CSR build = two-level LDS-binned counting sort, ZERO per-edge global
// atomics. Round-13: hops use PAIRED-NODE waves (32 lanes/node, lane =
// feature pair, bf16x2 packed 4B gathers) -> one gather instruction
// retires 2 edges, one ecw load serves both halves: VMEM ops/edge ~1.0
// (was ~2.2 with round-12's 8-wide padding).

constexpr int kN = 100000;
constexpr int kD = 64;
constexpr int BSHIFT = 9;                    // 512 nodes per coarse bucket
constexpr int NBUCK = (kN + 511) >> BSHIFT;  // 196
constexpr int CHUNK = 4096;                  // pass-A edges per block
constexpr int XW_ROWS = 128;                 // k_xw rows per block

__device__ __forceinline__ float bf2f(unsigned short u) {
    return __uint_as_float(((unsigned)u) << 16);
}
__device__ __forceinline__ unsigned short f2bf(float f) {  // RNE
    unsigned b = __float_as_uint(f);
    b += 0x7FFF + ((b >> 16) & 1);
    return (unsigned short)(b >> 16);
}

// ---- pass A1: per-block bucket histogram (no global atomics) ----
__global__ __launch_bounds__(256) void kA_count(const int* __restrict__ row,
                                                int* __restrict__ bc, int nblk, int E) {
    __shared__ int hist[256];
    int t = threadIdx.x;
    hist[t] = 0;
    __syncthreads();
    int g0 = blockIdx.x * CHUNK;
    int n = min(CHUNK, E - g0);
    for (int i = t; i < n; i += 256) {
        atomicAdd(&hist[row[g0 + i] >> BSHIFT], 1);
    }
    __syncthreads();
    if (t < NBUCK) bc[t * nblk + blockIdx.x] = hist[t];
}

// ---- pass A2a: per-bucket parallel exclusive scan over blocks ----
__global__ __launch_bounds__(256) void kA_scanB(int* __restrict__ bc,
                                                int* __restrict__ tot, int nblk) {
    __shared__ int sh[256];
    int b = blockIdx.x;
    int t = threadIdx.x;
    int* p = bc + (size_t)b * nblk;
    int ipt = (nblk + 255) >> 8;  // items per thread (1 for nblk<=256)
    int s0 = t * ipt;
    int s1 = min(s0 + ipt, nblk);
    int lsum = 0;
    for (int k = s0; k < s1; ++k) lsum += p[k];
    sh[t] = lsum;
    __syncthreads();
    for (int off = 1; off < 256; off <<= 1) {
        int add = (t >= off) ? sh[t - off] : 0;
        __syncthreads();
        sh[t] += add;
        __syncthreads();
    }
    int run = sh[t] - lsum;  // exclusive prefix of this thread's segment
    for (int k = s0; k < s1; ++k) {
        int v = p[k];
        p[k] = run;
        run += v;
    }
    if (t == 255) tot[b] = sh[255];
}

// ---- pass A2b: exclusive scan of bucket totals -> base[] ----
__global__ __launch_bounds__(256) void kA_scanT(const int* __restrict__ tot,
                                                int* __restrict__ base) {
    __shared__ int sh[256];
    int t = threadIdx.x;
    int v = (t < NBUCK) ? tot[t] : 0;
    sh[t] = v;
    __syncthreads();
    for (int off = 1; off < 256; off <<= 1) {
        int add = (t >= off) ? sh[t - off] : 0;
        __syncthreads();
        sh[t] += add;
        __syncthreads();
    }
    if (t < NBUCK) base[t] = sh[t] - v;
}

// ---- pass A3: bucket-major placement via LDS staging, coalesced run flush
// tmp[pos] = { col | (row&511)<<17 , w_bits }
__global__ __launch_bounds__(256) void kA_place(const int* __restrict__ row,
                                                const int* __restrict__ col,
                                                const float* __restrict__ w,
                                                const int* __restrict__ bc,
                                                const int* __restrict__ base, int nblk,
                                                int2* __restrict__ tmp, int E) {
    __shared__ int hist[256];
    __shared__ int lbase[256];
    __shared__ int gb[256];
    __shared__ int cur[256];
    __shared__ int2 stage[CHUNK];
    __shared__ unsigned char bkt[CHUNK];
    int t = threadIdx.x;
    hist[t] = 0;
    __syncthreads();
    int g0 = blockIdx.x * CHUNK;
    int n = min(CHUNK, E - g0);
    for (int i = t; i < n; i += 256) {
        atomicAdd(&hist[row[g0 + i] >> BSHIFT], 1);
    }
    __syncthreads();
    // exclusive scan hist -> lbase (local bucket starts within this chunk)
    int v = hist[t];
    lbase[t] = v;
    __syncthreads();
    for (int off = 1; off < 256; off <<= 1) {
        int add = (t >= off) ? lbase[t - off] : 0;
        __syncthreads();
        lbase[t] += add;
        __syncthreads();
    }
    int excl = lbase[t] - v;
    __syncthreads();
    lbase[t] = excl;
    cur[t] = excl;
    if (t < NBUCK) gb[t] = base[t] + bc[t * nblk + blockIdx.x];  // block's run start
    __syncthreads();
    // place edges bucket-major in LDS (LDS atomics only)
    for (int i = t; i < n; i += 256) {
        int r = row[g0 + i];
        int c = col[g0 + i];
        float wv = w[g0 + i];
        int b = r >> BSHIFT;
        int lp = atomicAdd(&cur[b], 1);
        stage[lp] = make_int2(c | ((r & 511) << 17), __float_as_int(wv));
        bkt[lp] = (unsigned char)b;
    }
    __syncthreads();
    // flush: consecutive i within a bucket run -> consecutive global addresses
    for (int i = t; i < n; i += 256) {
        int b = bkt[i];
        tmp[gb[b] + (i - lbase[b])] = stage[i];
    }
}

// ---- pass A4: per-bucket deg/dinv from tmp (LDS float atomics) ----
__global__ __launch_bounds__(512) void kD_deg(const int2* __restrict__ tmp,
                                              const int* __restrict__ base,
                                              float* __restrict__ dinv, int E) {
    __shared__ float degs[512];
    int b = blockIdx.x;
    int t = threadIdx.x;
    degs[t] = 0.0f;
    __syncthreads();
    int gbase = base[b];
    int gend = (b == NBUCK - 1) ? E : base[b + 1];
    int node0 = b << BSHIFT;
    int nloc = min(512, kN - node0);
    for (int i = gbase + t; i < gend; i += 512) {
        int2 e = tmp[i];
        atomicAdd(&degs[(e.x >> 17) & 511], __int_as_float(e.y));
    }
    __syncthreads();
    if (t < nloc) {
        float d = 1.0f + degs[t];
        dinv[node0 + t] = (d > 0.0f) ? rsqrtf(d) : 0.0f;
    }
}

// ---- pass B: per-bucket fine counting sort + start[] ----
// writes FINAL ecw = {byte offset col<<7, dinv[row]*w*dinv[col]} (dinv ready).
__global__ __launch_bounds__(512) void kB_sort(const int2* __restrict__ tmp,
                                               const int* __restrict__ base,
                                               const float* __restrict__ dinv,
                                               int2* __restrict__ ecw,
                                               int* __restrict__ start, int E) {
    __shared__ int hist[512];
    __shared__ int cur[512];
    int b = blockIdx.x;
    int t = threadIdx.x;
    int gbase = base[b];
    int gend = (b == NBUCK - 1) ? E : base[b + 1];
    int size = gend - gbase;
    int node0 = b << BSHIFT;
    int nloc = min(512, kN - node0);
    hist[t] = 0;
    __syncthreads();
    for (int i = t; i < size; i += 512) {
        atomicAdd(&hist[(tmp[gbase + i].x >> 17) & 511], 1);
    }
    __syncthreads();
    // exclusive scan hist -> cur
    int v = hist[t];
    hist[t] = v;
    __syncthreads();
    for (int off = 1; off < 512; off <<= 1) {
        int add = (t >= off) ? hist[t - off] : 0;
        __syncthreads();
        hist[t] += add;
        __syncthreads();
    }
    int excl = hist[t] - v;
    __syncthreads();
    cur[t] = excl;
    __syncthreads();
    if (t < nloc) start[node0 + t] = gbase + excl;
    if (b == 0 && t == 0) start[kN] = E;
    // scatter within bucket, applying full normalization
    for (int i = t; i < size; i += 512) {
        int2 e = tmp[gbase + i];
        int c = e.x & 0x1FFFF;
        int rl = (e.x >> 17) & 511;
        float wn = dinv[node0 + rl] * __int_as_float(e.y) * dinv[c];
        int lp = atomicAdd(&cur[rl], 1);
        ecw[gbase + lp] = make_int2(c << 7, __float_as_int(wn));
    }
}

// ---- y = x @ W (fp32 in, bf16 out) ----
// lane = output column (W column in 64 VGPRs); 128 x-rows staged in LDS;
// per row: 16 broadcast b128 LDS reads + 64 FMAs; 2 rows in flight.
__global__ __launch_bounds__(256) void k_xw(const float* __restrict__ x,
                                            const float* __restrict__ W,
                                            unsigned short* __restrict__ y, int n) {
    __shared__ float Xs[XW_ROWS][kD];
    int t = threadIdx.x;
    int lane = t & 63;
    int wv = t >> 6;  // wave id 0..3
    int row0 = blockIdx.x * XW_ROWS;
    float Wc[kD];
#pragma unroll
    for (int k = 0; k < kD; ++k) Wc[k] = W[k * kD + lane];
    for (int i = t; i < XW_ROWS * (kD / 4); i += 256) {
        int r = i >> 4;
        int q = i & 15;
        float4 v = make_float4(0.0f, 0.0f, 0.0f, 0.0f);
        if (row0 + r < n)
            v = *reinterpret_cast<const float4*>(x + (size_t)(row0 + r) * kD + q * 4);
        *reinterpret_cast<float4*>(&Xs[r][q * 4]) = v;
    }
    __syncthreads();
    int rbase = wv * 32;  // this wave's 32 rows
#pragma unroll
    for (int rr = 0; rr < 32; rr += 2) {
        int r0 = rbase + rr;
        float acc0 = 0.0f, acc1 = 0.0f;
#pragma unroll
        for (int q = 0; q < 16; ++q) {  // broadcast reads: all lanes same addr
            float4 a = *reinterpret_cast<const float4*>(&Xs[r0][q * 4]);
            float4 b = *reinterpret_cast<const float4*>(&Xs[r0 + 1][q * 4]);
            acc0 = fmaf(a.x, Wc[q * 4 + 0], acc0);
            acc1 = fmaf(b.x, Wc[q * 4 + 0], acc1);
            acc0 = fmaf(a.y, Wc[q * 4 + 1], acc0);
            acc1 = fmaf(b.y, Wc[q * 4 + 1], acc1);
            acc0 = fmaf(a.z, Wc[q * 4 + 2], acc0);
            acc1 = fmaf(b.z, Wc[q * 4 + 2], acc1);
            acc0 = fmaf(a.w, Wc[q * 4 + 3], acc0);
            acc1 = fmaf(b.w, Wc[q * 4 + 3], acc1);
        }
        int gr = row0 + r0;
        if (gr < n) y[(size_t)gr * kD + lane] = f2bf(acc0);
        if (gr + 1 < n) y[(size_t)(gr + 1) * kD + lane] = f2bf(acc1);
    }
}

// ---- paired-node gather hop: 2 nodes/wave, 32 lanes each, lane=feature pair
// Each lane loads a packed bf16x2 (4B). One gather instruction retires one
// edge for EACH half-wave. Loop count = max(degA, degB) via shfl_xor(d,32);
// padded slots clamp to the node's last edge (same line) with weight 0.
template <typename OutWriter>
__device__ __forceinline__ void hop_body(const int* __restrict__ start,
                                         const int2* __restrict__ ecw,
                                         const float* __restrict__ dinv,
                                         const unsigned short* __restrict__ h_in,
                                         int n, OutWriter writeout) {
    int wv = threadIdx.x >> 6;
    int lane = threadIdx.x & 63;
    int half = lane >> 5;  // which node of the pair
    int sub = lane & 31;   // feature pair index (features 2*sub, 2*sub+1)
    int node = blockIdx.x * 8 + wv * 2 + half;
    bool valid = node < n;
    int nd = valid ? node : (n - 1);  // safe address for inactive lanes
    const char* hb = (const char*)h_in;
    int lo = sub << 2;  // byte offset of the feature pair within a 128B row
    float di = dinv[nd];
    unsigned su = *(const unsigned*)(hb + ((size_t)nd << 7) + lo);
    float d2 = di * di;
    float acc0 = d2 * __uint_as_float(su << 16);
    float acc1 = d2 * __uint_as_float(su & 0xffff0000u);
    int s = start[nd], e = start[nd + 1];
    int d = e - s;
    int dmax = max(d, __shfl_xor(d, 32));  // uniform loop bound for the wave
    int em1 = max(e - 1, 0);               // clamp target (e==0 safe)
    for (int it = 0; it < dmax; it += 4) {
        int j = s + it;
        int2 v0 = ecw[min(j + 0, em1)];
        int2 v1 = ecw[min(j + 1, em1)];
        int2 v2 = ecw[min(j + 2, em1)];
        int2 v3 = ecw[min(j + 3, em1)];
        unsigned g0 = *(const unsigned*)(hb + (unsigned)(v0.x + lo));
        unsigned g1 = *(const unsigned*)(hb + (unsigned)(v1.x + lo));
        unsigned g2 = *(const unsigned*)(hb + (unsigned)(v2.x + lo));
        unsigned g3 = *(const unsigned*)(hb + (unsigned)(v3.x + lo));
        float w0 = (it + 0 < d) ? __int_as_float(v0.y) : 0.0f;
        float w1 = (it + 1 < d) ? __int_as_float(v1.y) : 0.0f;
        float w2 = (it + 2 < d) ? __int_as_float(v2.y) : 0.0f;
        float w3 = (it + 3 < d) ? __int_as_float(v3.y) : 0.0f;
        acc0 = fmaf(w0, __uint_as_float(g0 << 16), acc0);
        acc1 = fmaf(w0, __uint_as_float(g0 & 0xffff0000u), acc1);
        acc0 = fmaf(w1, __uint_as_float(g1 << 16), acc0);
        acc1 = fmaf(w1, __uint_as_float(g1 & 0xffff0000u), acc1);
        acc0 = fmaf(w2, __uint_as_float(g2 << 16), acc0);
        acc1 = fmaf(w2, __uint_as_float(g2 & 0xffff0000u), acc1);
        acc0 = fmaf(w3, __uint_as_float(g3 << 16), acc0);
        acc1 = fmaf(w3, __uint_as_float(g3 & 0xffff0000u), acc1);
    }
    if (valid) writeout(node, sub, acc0, acc1);
}

__global__ __launch_bounds__(256) void k_hop1(const int* __restrict__ start,
                                              const int2* __restrict__ ecw,
                                              const float* __restrict__ dinv,
                                              const unsigned short* __restrict__ h_in,
                                              unsigned* __restrict__ h_out32, int n) {
    hop_body(start, ecw, dinv, h_in, n,
             [=](int node, int sub, float a0, float a1) {
                 unsigned p = (unsigned)f2bf(a0) | ((unsigned)f2bf(a1) << 16);
                 h_out32[((size_t)node << 5) + sub] = p;
             });
}

__global__ __launch_bounds__(256) void k_hop2(const int* __restrict__ start,
                                              const int2* __restrict__ ecw,
                                              const float* __restrict__ dinv,
                                              const unsigned short* __restrict__ h_in,
                                              const float* __restrict__ bias,
                                              float* __restrict__ out, int n) {
    hop_body(start, ecw, dinv, h_in, n,
             [=](int node, int sub, float a0, float a1) {
                 float2 b = *reinterpret_cast<const float2*>(bias + 2 * sub);
                 float2 o = make_float2(a0 + b.x, a1 + b.y);
                 *reinterpret_cast<float2*>(out + ((size_t)node << 6) + 2 * sub) = o;
             });
}

extern "C" void kernel_launch(void* const* d_in, const int* in_sizes, int n_in,
                              void* d_out, int out_size, void* d_ws, size_t ws_size,
                              hipStream_t stream) {
    const float* x    = (const float*)d_in[0];   // (N, 64)
    const int*   ei   = (const int*)d_in[1];     // (2, E)
    const float* ew   = (const float*)d_in[2];   // (E,)
    const float* W    = (const float*)d_in[3];   // (64, 64)
    const float* bias = (const float*)d_in[4];   // (64,)
    const int E = in_sizes[1] / 2;
    const int* row = ei;       // destination
    const int* col = ei + E;   // source

    const int nblk = (E + CHUNK - 1) / CHUNK;  // pass-A blocks (245 @ E=1M)

    // ws layout (1KB-aligned): base[256] | tot[256] | bc[NBUCK*nblk] |
    // start[kN+1] | dinv[kN] | ecw[E] int2 | y bf16 | h1 bf16 (tmp aliases h1)
    char* ws = (char*)d_ws;
    auto alloc = [&](size_t bytes) {
        char* p = ws;
        ws += ((bytes + 1023) & ~(size_t)1023);
        return p;
    };
    int*            base  = (int*)alloc(sizeof(int) * 256);
    int*            tot   = (int*)alloc(sizeof(int) * 256);
    int*            bc    = (int*)alloc(sizeof(int) * (size_t)NBUCK * nblk);
    int*            start = (int*)alloc(sizeof(int) * (kN + 1));
    float*          dinv  = (float*)alloc(sizeof(float) * kN);
    int2*           ecw   = (int2*)alloc(sizeof(int2) * (size_t)E);
    unsigned short* y     = (unsigned short*)alloc(sizeof(short) * (size_t)kN * kD);
    unsigned short* h1    = (unsigned short*)alloc(sizeof(short) * (size_t)kN * kD);
    int2*           tmp   = (int2*)h1;  // bucket-major staging, dead before hop1

    // dense linear first: y = x @ W (bf16)
    k_xw<<<(kN + XW_ROWS - 1) / XW_ROWS, 256, 0, stream>>>(x, W, y, kN);

    // CSR build (no per-edge global atomics)
    kA_count<<<nblk, 256, 0, stream>>>(row, bc, nblk, E);
    kA_scanB<<<NBUCK, 256, 0, stream>>>(bc, tot, nblk);
    kA_scanT<<<1, 256, 0, stream>>>(tot, base);
    kA_place<<<nblk, 256, 0, stream>>>(row, col, ew, bc, base, nblk, tmp, E);
    kD_deg<<<NBUCK, 512, 0, stream>>>(tmp, base, dinv, E);
    kB_sort<<<NBUCK, 512, 0, stream>>>(tmp, base, dinv, ecw, start, E);

    // 2 gather hops (paired-node waves, packed bf16x2 gathers)
    k_hop1<<<(kN + 7) / 8, 256, 0, stream>>>(start, ecw, dinv, y,
                                             (unsigned*)h1, kN);
    k_hop2<<<(kN + 7) / 8, 256, 0, stream>>>(start, ecw, dinv, h1, bias,
                                             (float*)d_out, kN);
}

// Round 14
// 123.763 us; speedup vs baseline: 1.2064x; 1.1445x over previous
//
#include <hip/hip_runtime.h>

// SGC: out = A_norm^2 (x W) + bias   (linearity: A^2 x W = A^2 (xW)).
// N=100000 nodes, E=1000000 edges, D=64 features, fp32 in/out.
// CSR build = two-level LDS-binned counting sort, ZERO per-edge global
// atomics. Round-14: (1) QUAD-node hops: 16 lanes/node, lane = feature
// quad, bf16x4 8B gathers -> one gather + one ecw broadcast retire an
// edge-slot for 4 nodes (VMEM instr/edge ~0.5); clamps removed via a
// zeroed 256-entry ecw tail pad + weight predication. (2) k_xw fused
// with kA_count (block-role split) so the histogram overlaps the GEMM.

constexpr int kN = 100000;
constexpr int kD = 64;
constexpr int BSHIFT = 9;                    // 512 nodes per coarse bucket
constexpr int NBUCK = (kN + 511) >> BSHIFT;  // 196
constexpr int CHUNK = 4096;                  // pass-A edges per block
constexpr int XW_ROWS = 128;                 // k_xw rows per block
constexpr int ECW_PAD = 256;                 // zeroed tail pad (overrun-safe)

__device__ __forceinline__ float bf2f(unsigned short u) {
    return __uint_as_float(((unsigned)u) << 16);
}
__device__ __forceinline__ unsigned short f2bf(float f) {  // RNE
    unsigned b = __float_as_uint(f);
    b += 0x7FFF + ((b >> 16) & 1);
    return (unsigned short)(b >> 16);
}

// ---- fused: y = x@W (blocks [0,nxw)) + per-chunk bucket histogram ----
__global__ __launch_bounds__(256) void k_xw_count(const float* __restrict__ x,
                                                  const float* __restrict__ W,
                                                  unsigned short* __restrict__ y,
                                                  const int* __restrict__ row,
                                                  int* __restrict__ bc,
                                                  int nxw, int nblk, int n, int E) {
    __shared__ float Xs[XW_ROWS][kD];  // count role reuses first 1KB as hist
    int bid = blockIdx.x;
    int t = threadIdx.x;
    if (bid >= nxw) {
        // ---- histogram role (1 chunk of 4096 edges) ----
        int cb = bid - nxw;
        int* hist = (int*)&Xs[0][0];
        hist[t] = 0;
        __syncthreads();
        int g0 = cb * CHUNK;
        int nn = min(CHUNK, E - g0);
        for (int i = t; i < nn; i += 256) {
            atomicAdd(&hist[row[g0 + i] >> BSHIFT], 1);
        }
        __syncthreads();
        if (t < NBUCK) bc[t * nblk + cb] = hist[t];
        return;
    }
    // ---- GEMM role: lane = out column (W col in VGPRs), rows in LDS ----
    int lane = t & 63;
    int wv = t >> 6;
    int row0 = bid * XW_ROWS;
    float Wc[kD];
#pragma unroll
    for (int k = 0; k < kD; ++k) Wc[k] = W[k * kD + lane];
    for (int i = t; i < XW_ROWS * (kD / 4); i += 256) {
        int r = i >> 4;
        int q = i & 15;
        float4 v = make_float4(0.0f, 0.0f, 0.0f, 0.0f);
        if (row0 + r < n)
            v = *reinterpret_cast<const float4*>(x + (size_t)(row0 + r) * kD + q * 4);
        *reinterpret_cast<float4*>(&Xs[r][q * 4]) = v;
    }
    __syncthreads();
    int rbase = wv * 32;
#pragma unroll
    for (int rr = 0; rr < 32; rr += 2) {
        int r0 = rbase + rr;
        float acc0 = 0.0f, acc1 = 0.0f;
#pragma unroll
        for (int q = 0; q < 16; ++q) {  // broadcast reads
            float4 a = *reinterpret_cast<const float4*>(&Xs[r0][q * 4]);
            float4 b = *reinterpret_cast<const float4*>(&Xs[r0 + 1][q * 4]);
            acc0 = fmaf(a.x, Wc[q * 4 + 0], acc0);
            acc1 = fmaf(b.x, Wc[q * 4 + 0], acc1);
            acc0 = fmaf(a.y, Wc[q * 4 + 1], acc0);
            acc1 = fmaf(b.y, Wc[q * 4 + 1], acc1);
            acc0 = fmaf(a.z, Wc[q * 4 + 2], acc0);
            acc1 = fmaf(b.z, Wc[q * 4 + 2], acc1);
            acc0 = fmaf(a.w, Wc[q * 4 + 3], acc0);
            acc1 = fmaf(b.w, Wc[q * 4 + 3], acc1);
        }
        int gr = row0 + r0;
        if (gr < n) y[(size_t)gr * kD + lane] = f2bf(acc0);
        if (gr + 1 < n) y[(size_t)(gr + 1) * kD + lane] = f2bf(acc1);
    }
}

// ---- pass A2a: per-bucket parallel exclusive scan over blocks ----
__global__ __launch_bounds__(256) void kA_scanB(int* __restrict__ bc,
                                                int* __restrict__ tot, int nblk) {
    __shared__ int sh[256];
    int b = blockIdx.x;
    int t = threadIdx.x;
    int* p = bc + (size_t)b * nblk;
    int ipt = (nblk + 255) >> 8;
    int s0 = t * ipt;
    int s1 = min(s0 + ipt, nblk);
    int lsum = 0;
    for (int k = s0; k < s1; ++k) lsum += p[k];
    sh[t] = lsum;
    __syncthreads();
    for (int off = 1; off < 256; off <<= 1) {
        int add = (t >= off) ? sh[t - off] : 0;
        __syncthreads();
        sh[t] += add;
        __syncthreads();
    }
    int run = sh[t] - lsum;
    for (int k = s0; k < s1; ++k) {
        int v = p[k];
        p[k] = run;
        run += v;
    }
    if (t == 255) tot[b] = sh[255];
}

// ---- pass A2b: exclusive scan of bucket totals -> base[]; zero ecw pad ----
__global__ __launch_bounds__(256) void kA_scanT(const int* __restrict__ tot,
                                                int* __restrict__ base,
                                                int2* __restrict__ ecw_pad) {
    __shared__ int sh[256];
    int t = threadIdx.x;
    int v = (t < NBUCK) ? tot[t] : 0;
    sh[t] = v;
    __syncthreads();
    for (int off = 1; off < 256; off <<= 1) {
        int add = (t >= off) ? sh[t - off] : 0;
        __syncthreads();
        sh[t] += add;
        __syncthreads();
    }
    if (t < NBUCK) base[t] = sh[t] - v;
    ecw_pad[t] = make_int2(0, 0);  // gather-overrun region, weight 0
}

// ---- pass A3: bucket-major placement via LDS staging, coalesced run flush
// tmp[pos] = { col | (row&511)<<17 , w_bits }
__global__ __launch_bounds__(256) void kA_place(const int* __restrict__ row,
                                                const int* __restrict__ col,
                                                const float* __restrict__ w,
                                                const int* __restrict__ bc,
                                                const int* __restrict__ base, int nblk,
                                                int2* __restrict__ tmp, int E) {
    __shared__ int hist[256];
    __shared__ int lbase[256];
    __shared__ int gb[256];
    __shared__ int cur[256];
    __shared__ int2 stage[CHUNK];
    __shared__ unsigned char bkt[CHUNK];
    int t = threadIdx.x;
    hist[t] = 0;
    __syncthreads();
    int g0 = blockIdx.x * CHUNK;
    int n = min(CHUNK, E - g0);
    for (int i = t; i < n; i += 256) {
        atomicAdd(&hist[row[g0 + i] >> BSHIFT], 1);
    }
    __syncthreads();
    int v = hist[t];
    lbase[t] = v;
    __syncthreads();
    for (int off = 1; off < 256; off <<= 1) {
        int add = (t >= off) ? lbase[t - off] : 0;
        __syncthreads();
        lbase[t] += add;
        __syncthreads();
    }
    int excl = lbase[t] - v;
    __syncthreads();
    lbase[t] = excl;
    cur[t] = excl;
    if (t < NBUCK) gb[t] = base[t] + bc[t * nblk + blockIdx.x];
    __syncthreads();
    for (int i = t; i < n; i += 256) {
        int r = row[g0 + i];
        int c = col[g0 + i];
        float wv = w[g0 + i];
        int b = r >> BSHIFT;
        int lp = atomicAdd(&cur[b], 1);
        stage[lp] = make_int2(c | ((r & 511) << 17), __float_as_int(wv));
        bkt[lp] = (unsigned char)b;
    }
    __syncthreads();
    for (int i = t; i < n; i += 256) {
        int b = bkt[i];
        tmp[gb[b] + (i - lbase[b])] = stage[i];
    }
}

// ---- pass A4: per-bucket deg/dinv from tmp (LDS float atomics) ----
__global__ __launch_bounds__(512) void kD_deg(const int2* __restrict__ tmp,
                                              const int* __restrict__ base,
                                              float* __restrict__ dinv, int E) {
    __shared__ float degs[512];
    int b = blockIdx.x;
    int t = threadIdx.x;
    degs[t] = 0.0f;
    __syncthreads();
    int gbase = base[b];
    int gend = (b == NBUCK - 1) ? E : base[b + 1];
    int node0 = b << BSHIFT;
    int nloc = min(512, kN - node0);
    for (int i = gbase + t; i < gend; i += 512) {
        int2 e = tmp[i];
        atomicAdd(&degs[(e.x >> 17) & 511], __int_as_float(e.y));
    }
    __syncthreads();
    if (t < nloc) {
        float d = 1.0f + degs[t];
        dinv[node0 + t] = (d > 0.0f) ? rsqrtf(d) : 0.0f;
    }
}

// ---- pass B: per-bucket fine counting sort + start[] ----
// writes FINAL ecw = {byte offset col<<7, dinv[row]*w*dinv[col]}.
__global__ __launch_bounds__(512) void kB_sort(const int2* __restrict__ tmp,
                                               const int* __restrict__ base,
                                               const float* __restrict__ dinv,
                                               int2* __restrict__ ecw,
                                               int* __restrict__ start, int E) {
    __shared__ int hist[512];
    __shared__ int cur[512];
    int b = blockIdx.x;
    int t = threadIdx.x;
    int gbase = base[b];
    int gend = (b == NBUCK - 1) ? E : base[b + 1];
    int size = gend - gbase;
    int node0 = b << BSHIFT;
    int nloc = min(512, kN - node0);
    hist[t] = 0;
    __syncthreads();
    for (int i = t; i < size; i += 512) {
        atomicAdd(&hist[(tmp[gbase + i].x >> 17) & 511], 1);
    }
    __syncthreads();
    int v = hist[t];
    hist[t] = v;
    __syncthreads();
    for (int off = 1; off < 512; off <<= 1) {
        int add = (t >= off) ? hist[t - off] : 0;
        __syncthreads();
        hist[t] += add;
        __syncthreads();
    }
    int excl = hist[t] - v;
    __syncthreads();
    cur[t] = excl;
    __syncthreads();
    if (t < nloc) start[node0 + t] = gbase + excl;
    if (b == 0 && t == 0) start[kN] = E;
    for (int i = t; i < size; i += 512) {
        int2 e = tmp[gbase + i];
        int c = e.x & 0x1FFFF;
        int rl = (e.x >> 17) & 511;
        float wn = dinv[node0 + rl] * __int_as_float(e.y) * dinv[c];
        int lp = atomicAdd(&cur[rl], 1);
        ecw[gbase + lp] = make_int2(c << 7, __float_as_int(wn));
    }
}

// ---- quad-node gather hop: 4 nodes/wave, 16 lanes each, lane=feature quad
// Each lane loads a packed bf16x4 (8B). One gather + one ecw broadcast
// retire an edge-slot for all 4 nodes. Loop bound = max degree of the 4;
// overrun reads land in a neighbor's segment / zeroed pad with weight
// predicated to 0 (exact).
template <typename OutWriter>
__device__ __forceinline__ void hop_body(const int* __restrict__ start,
                                         const int2* __restrict__ ecw,
                                         const float* __restrict__ dinv,
                                         const unsigned short* __restrict__ h_in,
                                         int n, OutWriter writeout) {
    int wv = threadIdx.x >> 6;
    int lane = threadIdx.x & 63;
    int q = lane >> 4;   // node-in-wave 0..3
    int f = lane & 15;   // feature quad (features 4f..4f+3)
    int node = blockIdx.x * 16 + wv * 4 + q;
    bool valid = node < n;
    int nd = valid ? node : (n - 1);
    const char* hb = (const char*)h_in;
    int lo = f << 3;  // byte offset of the feature quad in a 128B row
    float di = dinv[nd];
    float d2 = di * di;
    uint2 su = *(const uint2*)(hb + ((size_t)nd << 7) + lo);
    float acc0 = d2 * __uint_as_float(su.x << 16);
    float acc1 = d2 * __uint_as_float(su.x & 0xffff0000u);
    float acc2 = d2 * __uint_as_float(su.y << 16);
    float acc3 = d2 * __uint_as_float(su.y & 0xffff0000u);
    int s = start[nd], e = start[nd + 1];
    int d = e - s;
    int m1 = max(d, __shfl_xor(d, 16));
    int dmax = max(m1, __shfl_xor(m1, 32));  // uniform loop bound
    for (int it = 0; it < dmax; it += 4) {
        int j = s + it;
        int2 v0 = ecw[j + 0];  // unconditional: tail pad makes overrun safe
        int2 v1 = ecw[j + 1];
        int2 v2 = ecw[j + 2];
        int2 v3 = ecw[j + 3];
        uint2 g0 = *(const uint2*)(hb + (unsigned)(v0.x + lo));
        uint2 g1 = *(const uint2*)(hb + (unsigned)(v1.x + lo));
        uint2 g2 = *(const uint2*)(hb + (unsigned)(v2.x + lo));
        uint2 g3 = *(const uint2*)(hb + (unsigned)(v3.x + lo));
        float w0 = (it + 0 < d) ? __int_as_float(v0.y) : 0.0f;
        float w1 = (it + 1 < d) ? __int_as_float(v1.y) : 0.0f;
        float w2 = (it + 2 < d) ? __int_as_float(v2.y) : 0.0f;
        float w3 = (it + 3 < d) ? __int_as_float(v3.y) : 0.0f;
        acc0 = fmaf(w0, __uint_as_float(g0.x << 16), acc0);
        acc1 = fmaf(w0, __uint_as_float(g0.x & 0xffff0000u), acc1);
        acc2 = fmaf(w0, __uint_as_float(g0.y << 16), acc2);
        acc3 = fmaf(w0, __uint_as_float(g0.y & 0xffff0000u), acc3);
        acc0 = fmaf(w1, __uint_as_float(g1.x << 16), acc0);
        acc1 = fmaf(w1, __uint_as_float(g1.x & 0xffff0000u), acc1);
        acc2 = fmaf(w1, __uint_as_float(g1.y << 16), acc2);
        acc3 = fmaf(w1, __uint_as_float(g1.y & 0xffff0000u), acc3);
        acc0 = fmaf(w2, __uint_as_float(g2.x << 16), acc0);
        acc1 = fmaf(w2, __uint_as_float(g2.x & 0xffff0000u), acc1);
        acc2 = fmaf(w2, __uint_as_float(g2.y << 16), acc2);
        acc3 = fmaf(w2, __uint_as_float(g2.y & 0xffff0000u), acc3);
        acc0 = fmaf(w3, __uint_as_float(g3.x << 16), acc0);
        acc1 = fmaf(w3, __uint_as_float(g3.x & 0xffff0000u), acc1);
        acc2 = fmaf(w3, __uint_as_float(g3.y << 16), acc2);
        acc3 = fmaf(w3, __uint_as_float(g3.y & 0xffff0000u), acc3);
    }
    if (valid) writeout(node, f, acc0, acc1, acc2, acc3);
}

__global__ __launch_bounds__(256) void k_hop1(const int* __restrict__ start,
                                              const int2* __restrict__ ecw,
                                              const float* __restrict__ dinv,
                                              const unsigned short* __restrict__ h_in,
                                              uint2* __restrict__ h_out64, int n) {
    hop_body(start, ecw, dinv, h_in, n,
             [=](int node, int f, float a0, float a1, float a2, float a3) {
                 uint2 p;
                 p.x = (unsigned)f2bf(a0) | ((unsigned)f2bf(a1) << 16);
                 p.y = (unsigned)f2bf(a2) | ((unsigned)f2bf(a3) << 16);
                 h_out64[((size_t)node << 4) + f] = p;  // 16 uint2 per row
             });
}

__global__ __launch_bounds__(256) void k_hop2(const int* __restrict__ start,
                                              const int2* __restrict__ ecw,
                                              const float* __restrict__ dinv,
                                              const unsigned short* __restrict__ h_in,
                                              const float* __restrict__ bias,
                                              float* __restrict__ out, int n) {
    hop_body(start, ecw, dinv, h_in, n,
             [=](int node, int f, float a0, float a1, float a2, float a3) {
                 float4 b = *reinterpret_cast<const float4*>(bias + (f << 2));
                 float4 o = make_float4(a0 + b.x, a1 + b.y, a2 + b.z, a3 + b.w);
                 *reinterpret_cast<float4*>(out + ((size_t)node << 6) + (f << 2)) = o;
             });
}

extern "C" void kernel_launch(void* const* d_in, const int* in_sizes, int n_in,
                              void* d_out, int out_size, void* d_ws, size_t ws_size,
                              hipStream_t stream) {
    const float* x    = (const float*)d_in[0];   // (N, 64)
    const int*   ei   = (const int*)d_in[1];     // (2, E)
    const float* ew   = (const float*)d_in[2];   // (E,)
    const float* W    = (const float*)d_in[3];   // (64, 64)
    const float* bias = (const float*)d_in[4];   // (64,)
    const int E = in_sizes[1] / 2;
    const int* row = ei;       // destination
    const int* col = ei + E;   // source

    const int nblk = (E + CHUNK - 1) / CHUNK;        // 245 @ E=1M
    const int nxw  = (kN + XW_ROWS - 1) / XW_ROWS;   // 782

    // ws layout (1KB-aligned): base[256] | tot[256] | bc[NBUCK*nblk] |
    // start[kN+1] | dinv[kN] | ecw[E+pad] int2 | y bf16 | h1 bf16 (tmp=h1)
    char* ws = (char*)d_ws;
    auto alloc = [&](size_t bytes) {
        char* p = ws;
        ws += ((bytes + 1023) & ~(size_t)1023);
        return p;
    };
    int*            base  = (int*)alloc(sizeof(int) * 256);
    int*            tot   = (int*)alloc(sizeof(int) * 256);
    int*            bc    = (int*)alloc(sizeof(int) * (size_t)NBUCK * nblk);
    int*            start = (int*)alloc(sizeof(int) * (kN + 1));
    float*          dinv  = (float*)alloc(sizeof(float) * kN);
    int2*           ecw   = (int2*)alloc(sizeof(int2) * (size_t)(E + ECW_PAD));
    unsigned short* y     = (unsigned short*)alloc(sizeof(short) * (size_t)kN * kD);
    unsigned short* h1    = (unsigned short*)alloc(sizeof(short) * (size_t)kN * kD);
    int2*           tmp   = (int2*)h1;  // bucket-major staging, dead before hop1

    // fused: y = x@W  ||  per-chunk bucket histogram
    k_xw_count<<<nxw + nblk, 256, 0, stream>>>(x, W, y, row, bc, nxw, nblk, kN, E);

    // CSR build (no per-edge global atomics)
    kA_scanB<<<NBUCK, 256, 0, stream>>>(bc, tot, nblk);
    kA_scanT<<<1, 256, 0, stream>>>(tot, base, ecw + E);
    kA_place<<<nblk, 256, 0, stream>>>(row, col, ew, bc, base, nblk, tmp, E);
    kD_deg<<<NBUCK, 512, 0, stream>>>(tmp, base, dinv, E);
    kB_sort<<<NBUCK, 512, 0, stream>>>(tmp, base, dinv, ecw, start, E);

    // 2 gather hops (quad-node waves, packed bf16x4 gathers)
    k_hop1<<<(kN + 15) / 16, 256, 0, stream>>>(start, ecw, dinv, y,
                                               (uint2*)h1, kN);
    k_hop2<<<(kN + 15) / 16, 256, 0, stream>>>(start, ecw, dinv, h1, bias,
                                               (float*)d_out, kN);
}